// Round 8
// baseline (4444.468 us; speedup 1.0000x reference)
//
#include <hip/hip_runtime.h>
#include <math.h>

#define N_PTS       40000
#define N_ANCH      4000     // ceil(0.1 * 40000)
#define KNN         20
#define NFB         128      // fps blocks (1 wave each)
#define BT          64       // threads per block (all blocks) = 1 wave
#define NWAVES      128                // fps waves
#define STRIDE      (NWAVES * 64)      // 8192 = 2^13
#define PPT         5                  // 8192*5 = 40960 >= 40000
#define TW          8                  // published candidates per WAVE (deep bound, R7: B~62)
#define POOL        (NWAVES * TW)      // 1024
#define RSLOTS      (POOL / 64)        // 16 readback entries per lane
#define CCAP        14                 // compacted capacity/lane (896 = 7/wave hard bound)

typedef unsigned long long ull;

#define LD_RLX(p)    __hip_atomic_load((p),  __ATOMIC_RELAXED, __HIP_MEMORY_SCOPE_AGENT)
#define ST_REL(p,v)  __hip_atomic_store((p), (v), __ATOMIC_RELEASE, __HIP_MEMORY_SCOPE_AGENT)
#define ST_RLX(p,v)  __hip_atomic_store((p), (v), __ATOMIC_RELAXED, __HIP_MEMORY_SCOPE_AGENT)

// Workspace layout:
//   off     0 : double acc               (zeroed)
//   off    64 : int flag[128]            (zeroed; per-wave monotone batch counters)
//   off  1024 : ull slots[2][1024]       (parity x pool, packed {val48|idx16}; 16 KB)
//   off 17408 : int anchors[4000]        (memset 0xFF -> -1)
//
// Protocol (R7 lesson): poll footprint must be MINIMAL. Publish 8 packed
// slots -> release-store flag (drains slot stores) -> poll 128 flags
// (2 words/lane) -> read pool ONCE. Self-tagged full-pool polling (R7)
// exploded per-batch cost 6->38us from coherent-read contention.

#define PK_VMASK 0xFFFFFFFFFFFF0000ull   // top 48 bits: value field

__device__ __forceinline__ double dist64(double px, double py, double pz,
                                         double wx, double wy, double wz) {
  double dx = px - wx, dy = py - wy, dz = pz - wz;
  return dx * dx + dy * dy + dz * dz;
}

// monotone u32 bucket key from f64 (order-preserving on high-32 buckets)
__device__ __forceinline__ unsigned key32(double v) {
  unsigned hi = (unsigned)__double2hiint(v);
  return (hi & 0x80000000u) ? ~hi : (hi | 0x80000000u);
}

// packed sort key: (value-desc, idx-asc) as ONE u64 (R6-verified, absmax 0).
//   pk = (monotone64(v) & ~0xFFFF) | ((0xFFFF - idx) & 0xFFFF)
__device__ __forceinline__ ull pack_key(double v, int idx) {
  ull b = (ull)__double_as_longlong(v);
  ull m = (b >> 63) ? ~b : (b | 0x8000000000000000ull);
  return (m & PK_VMASK) | ((ull)(0xFFFF - idx) & 0xFFFFull);
}

// wave-wide max of u32 via DPP (VALU only); returns wave-uniform max
__device__ __forceinline__ unsigned wave_umax_dpp(unsigned x) {
#define DPP_STEP(ctrl) { unsigned y = (unsigned)__builtin_amdgcn_update_dpp( \
      0, (int)x, ctrl, 0xf, 0xf, true); x = (y > x) ? y : x; }
  DPP_STEP(0x111)  // row_shr:1
  DPP_STEP(0x112)  // row_shr:2
  DPP_STEP(0x114)  // row_shr:4
  DPP_STEP(0x118)  // row_shr:8
  DPP_STEP(0x142)  // row_bcast:15
  DPP_STEP(0x143)  // row_bcast:31
#undef DPP_STEP
  return (unsigned)__builtin_amdgcn_readlane((int)x, 63);
}

__device__ __forceinline__ int rl_i(int v, int l) { return __builtin_amdgcn_readlane(v, l); }
__device__ __forceinline__ float rl_f(float v, int l) {
  return __int_as_float(__builtin_amdgcn_readlane(__float_as_int(v), l));
}
__device__ __forceinline__ double rl_d(double v, int l) {
  int lo = __builtin_amdgcn_readlane(__double2loint(v), l);
  int hi = __builtin_amdgcn_readlane(__double2hiint(v), l);
  return __hiloint2double(hi, lo);
}
__device__ __forceinline__ ull rl_u64(ull v, int l) {
  int lo = __builtin_amdgcn_readlane((int)(unsigned)(v & 0xffffffffull), l);
  int hi = __builtin_amdgcn_readlane((int)(unsigned)(v >> 32), l);
  return ((ull)(unsigned)hi << 32) | (unsigned)lo;
}

// exact wave argmax (value desc, idx asc) — rare fallback path
__device__ __forceinline__ void wave_argmax_exact(double& wv, int& wix) {
#pragma unroll
  for (int off = 1; off < 64; off <<= 1) {
    double ov = __shfl_xor(wv, off);
    int    oi = __shfl_xor(wix, off);
    bool bt = (ov > wv) || (ov == wv && oi < wix);
    wv = bt ? ov : wv; wix = bt ? oi : wix;
  }
}

// wave winner of (v desc, idx asc): wave-uniform (wkey, wlane, widx). Exact.
__device__ __forceinline__ void wave_pick(double v, int idx,
                                          unsigned& wkey, int& wlane, int& widx) {
  unsigned k = key32(v);
  unsigned M = wave_umax_dpp(k);
  ull mask = __ballot(k == M);
  if (__popcll(mask) == 1) {
    wlane = __ffsll(mask) - 1;
    widx  = rl_i(idx, wlane);
    wkey  = M;
  } else {
    double wv = v; int wi = idx;
    wave_argmax_exact(wv, wi);
    widx = wi;
    wkey = key32(wv);
    ull m2 = __ballot(idx == widx);
    wlane = __ffsll(m2) - 1;
  }
}

struct FpsSm {                 // single-wave compaction buffers (17920 B)
  ull    lv[CCAP * 64];        // packed keys
  float  lc[CCAP * 64][3];
};
struct KnnSm { int w[KNN]; };
union Smem { FpsSm f; KnnSm k; };

// ============== symmetric 3x3: eigenvector of largest eigenvalue ===========
__device__ static inline void eig3_maxvec(double xx, double xy, double xz,
                                          double yy, double yz, double zz,
                                          double& v0, double& v1, double& v2) {
  double q  = (xx + yy + zz) / 3.0;
  double p1 = xy * xy + xz * xz + yz * yz;
  double a00 = xx - q, a11 = yy - q, a22 = zz - q;
  double p2 = a00 * a00 + a11 * a11 + a22 * a22 + 2.0 * p1;
  if (p2 < 1e-300) { v0 = 1.0; v1 = 0.0; v2 = 0.0; return; }
  double p   = sqrt(p2 / 6.0);
  double inv = 1.0 / p;
  double b00 = a00 * inv, b01 = xy * inv, b02 = xz * inv;
  double b11 = a11 * inv, b12 = yz * inv, b22 = a22 * inv;
  double detB = b00 * (b11 * b22 - b12 * b12)
              - b01 * (b01 * b22 - b12 * b02)
              + b02 * (b01 * b12 - b11 * b02);
  double r = fmin(1.0, fmax(-1.0, detB * 0.5));
  double phi = acos(r) / 3.0;
  double lam = q + 2.0 * p * cos(phi);   // largest eigenvalue

  double r0x = xx - lam, r0y = xy,       r0z = xz;
  double r1x = xy,       r1y = yy - lam, r1z = yz;
  double r2x = xz,       r2y = yz,       r2z = zz - lam;
  double c0x = r0y * r1z - r0z * r1y, c0y = r0z * r1x - r0x * r1z, c0z = r0x * r1y - r0y * r1x;
  double c1x = r0y * r2z - r0z * r2y, c1y = r0z * r2x - r0x * r2z, c1z = r0x * r2y - r0y * r2x;
  double c2x = r1y * r2z - r1z * r2y, c2y = r1z * r2x - r1x * r2z, c2z = r1x * r2y - r1y * r2x;
  double n0 = c0x * c0x + c0y * c0y + c0z * c0z;
  double n1 = c1x * c1x + c1y * c1y + c1z * c1z;
  double n2 = c2x * c2x + c2y * c2y + c2z * c2z;
  double bx = c0x, by = c0y, bz = c0z, bn = n0;
  if (n1 > bn) { bx = c1x; by = c1y; bz = c1z; bn = n1; }
  if (n2 > bn) { bx = c2x; by = c2y; bz = c2z; bn = n2; }
  if (bn < 1e-280) { v0 = 1.0; v1 = 0.0; v2 = 0.0; return; }
  double s = 1.0 / sqrt(bn);
  v0 = bx * s; v1 = by * s; v2 = bz * s;
}

// ===========================================================================
__global__ __launch_bounds__(BT, 2) void fps_knn_kernel(
    const float* __restrict__ pos, const float* __restrict__ vec_pred,
    int* __restrict__ flag, ull* __restrict__ slots,
    int* __restrict__ anchors, double* __restrict__ acc) {
  __shared__ Smem sm;
  const int lane = threadIdx.x & 63;

  if (blockIdx.x < NFB) {
    // ============ FPS: one wave per block, wave-autonomous ================
    __builtin_amdgcn_s_setprio(1);   // FPS is the critical path (R0: +2-3%)

    const int gw   = blockIdx.x;       // global wave id, 0..127
    const int gtid = gw * 64 + lane;

    double pdx[PPT], pdy[PPT], pdz[PPT], md[PPT];   // f64 coords in regs
    const double a0x = (double)pos[0], a0y = (double)pos[1], a0z = (double)pos[2];
#pragma unroll
    for (int k = 0; k < PPT; ++k) {
      int i = gtid + k * STRIDE;
      if (i < N_PTS) {
        pdx[k] = (double)pos[3 * i];
        pdy[k] = (double)pos[3 * i + 1];
        pdz[k] = (double)pos[3 * i + 2];
        md[k]  = dist64(pdx[k], pdy[k], pdz[k], a0x, a0y, a0z);
      } else {
        pdx[k] = 0.0; pdy[k] = 0.0; pdz[k] = 0.0;
        md[k]  = -1.0e300;   // pad: never beats real md >= 0
      }
    }
    if (gw == 0 && lane == 0) ST_RLX(anchors + 0, 0);

    double bv = -1.0e301; int bi = 0x7fffffff;
#pragma unroll
    for (int k = 0; k < PPT; ++k) {
      int i = gtid + k * STRIDE;
      bool bt = (md[k] > bv) || (md[k] == bv && i < bi);
      bv = bt ? md[k] : bv; bi = bt ? i : bi;
    }

    int nsel  = 1;
    int batch = 0;
#pragma unroll 1
    while (nsel < N_ANCH) {
      batch++;
      const int par = batch & 1;

      // ---- per-wave top-8 extraction (exact lex order) ----
      unsigned cons = 0;
      double pv = -1.0e301; int pix = 0;
#pragma unroll 1
      for (int r = 0; r < TW; ++r) {
        unsigned wkey; int wlane, widx;
        wave_pick(bv, bi, wkey, wlane, widx);
        double wval = rl_d(bv, wlane);
        if (lane == wlane && bi != 0x7fffffff) {
          cons |= 1u << ((unsigned)(bi - gtid) >> 13);   // STRIDE = 2^13
          bv = -1.0e301; bi = 0x7fffffff;
#pragma unroll
          for (int k = 0; k < PPT; ++k) {
            if (!((cons >> k) & 1u)) {
              int i = gtid + k * STRIDE;
              bool bt = (md[k] > bv) || (md[k] == bv && i < bi);
              bv = bt ? md[k] : bv; bi = bt ? i : bi;
            }
          }
        }
        if (lane == r) { pv = wval; pix = widx; }
      }

      // ---- publish: ONE packed 8B store/lane; lane0 release flag orders ----
      if (lane < TW) {
        ST_RLX(&slots[par * POOL + gw * TW + lane], pack_key(pv, pix));
      }
      if (lane == 0) ST_REL(flag + gw, batch);   // s_waitcnt vmcnt(0) + store

      // ---- poll all 128 wave-flags (minimal footprint: 2 words/lane) -----
      for (;;) {
        int f0 = LD_RLX(flag + lane);
        int f1 = LD_RLX(flag + 64 + lane);
        if (__ballot((f0 >= batch) && (f1 >= batch)) == ~0ull) break;
        __builtin_amdgcn_s_sleep(1);
      }
      __builtin_amdgcn_sched_barrier(0);   // no compiler motion across the poll

      // ---- readback pool ONCE: packed u64 x 16 entries/lane ----
      ull pk[RSLOTS];
#pragma unroll
      for (int j = 0; j < RSLOTS; ++j)
        pk[j] = LD_RLX(&slots[par * POOL + lane + 64 * j]);

      // ---- bucket keys; Mkey (global max bucket) and BmaxKey ----
      // entry e = lane + 64*j; e % 8 == lane % 8, so lanes with (lane&7)==7
      // hold exactly the 8th-published entries of all waves.
      unsigned kj[RSLOTS];
      unsigned lkmax = 0;
#pragma unroll
      for (int j = 0; j < RSLOTS; ++j) {
        kj[j] = (unsigned)(pk[j] >> 32);
        lkmax = (kj[j] > lkmax) ? kj[j] : lkmax;
      }
      const unsigned Mkey    = wave_umax_dpp(lkmax);
      const unsigned BmaxKey = wave_umax_dpp(((lane & 7) == 7) ? lkmax : 0u);

      int cap = N_ANCH - nsel;
      int S = 0;

      if (Mkey > BmaxKey) {
        // -------- typical path: compact live entries (bucket > BmaxKey) ----
        // each wave's own 8th entry key <= BmaxKey -> <= 7 live per wave
        // -> live_n <= 896 = CCAP*64.
        int base = 0;
#pragma unroll
        for (int j = 0; j < RSLOTS; ++j) {
          bool live = kj[j] > BmaxKey;
          ull bal = __ballot(live);
          int rank = base + (int)__popcll(bal & ((1ull << lane) - 1ull));
          if (live) {
            sm.f.lv[rank] = pk[j];
            int p = 0xFFFF - (int)(pk[j] & 0xFFFFull);
            sm.f.lc[rank][0] = pos[3 * p];
            sm.f.lc[rank][1] = pos[3 * p + 1];
            sm.f.lc[rank][2] = pos[3 * p + 2];
          }
          base += (int)__popcll(bal);
        }
        const int live_n = base;   // wave-uniform, 1..896

        // BRANCHLESS load: always read all CCAP slots (arrays sized CCAP*64,
        // stale entries masked by ok-select). R7 lesson: runtime live_n
        // guards = ~42 scalar branches/selection, worse than the work saved.
        ull pk2[CCAP]; float c2x[CCAP], c2y[CCAP], c2z[CCAP];
#pragma unroll
        for (int tt = 0; tt < CCAP; ++tt) {
          int e = tt * 64 + lane;
          bool ok = e < live_n;
          ull    v  = sm.f.lv[e];
          float  x  = sm.f.lc[e][0];
          float  y  = sm.f.lc[e][1];
          float  z  = sm.f.lc[e][2];
          pk2[tt] = ok ? v : 0ull;
          c2x[tt] = ok ? x : 0.0f;
          c2y[tt] = ok ? y : 0.0f;
          c2z[tt] = ok ? z : 0.0f;
        }

        // ---- S-loop: branchless integer-key chain; md updated inline
        // (R4 lesson). Dead slots (pk2=0) are algebraically inert: their
        // update key >= 2^63 > 0 so min keeps 0; winner key > BmaxKey >= 0
        // so winner-kill can't match a dead slot.
#pragma unroll 1
        while (S < cap) {
          ull wpk = pk2[0]; float fx = c2x[0], fy = c2y[0], fz = c2z[0];
#pragma unroll
          for (int tt = 1; tt < CCAP; ++tt) {
            bool t = pk2[tt] > wpk;
            wpk = t ? pk2[tt] : wpk;
            fx = t ? c2x[tt] : fx; fy = t ? c2y[tt] : fy; fz = t ? c2z[tt] : fz;
          }

          // wave winner via u32 DPP on the packed key's top 32 bits
          unsigned k = (unsigned)(wpk >> 32);
          unsigned M = wave_umax_dpp(k);
          ull mask = __ballot(k == M);
          ull full; int wlane;
          if (__popcll(mask) == 1) {
            wlane = __ffsll(mask) - 1;
            full  = rl_u64(wpk, wlane);
          } else {
            // bucket tie: butterfly max on the full packed key (exact)
            ull g = wpk;
#pragma unroll
            for (int off = 1; off < 64; off <<= 1) {
              ull o = __shfl_xor(g, off);
              g = (o > g) ? o : g;
            }
            full = g;
            ull m2 = __ballot(wpk == full);
            wlane = __ffsll(m2) - 1;
          }
          unsigned wkey = (unsigned)(full >> 32);
          if (S != 0 && !(wkey > BmaxKey)) break;
          int widx = 0xFFFF - (int)(full & 0xFFFFull);
          double wxd = (double)rl_f(fx, wlane);
          double wyd = (double)rl_f(fy, wlane);
          double wzd = (double)rl_f(fz, wlane);
          if (gw == 0 && lane == 0) ST_RLX(anchors + nsel + S, widx);

          // branchless update over all CCAP slots
#pragma unroll
          for (int tt = 0; tt < CCAP; ++tt) {
            double d = dist64((double)c2x[tt], (double)c2y[tt], (double)c2z[tt],
                              wxd, wyd, wzd);
            ull db  = (ull)__double_as_longlong(d);
            ull dpk = ((db | 0x8000000000000000ull) & PK_VMASK)
                    | (pk2[tt] & 0xFFFFull);
            ull nv  = (dpk < pk2[tt]) ? dpk : pk2[tt];
            pk2[tt] = (pk2[tt] == full) ? 0ull : nv;
          }
          // inline apply to own md slice (bubble-filler under the chain)
#pragma unroll
          for (int k2 = 0; k2 < PPT; ++k2)
            md[k2] = fmin(md[k2], dist64(pdx[k2], pdy[k2], pdz[k2], wxd, wyd, wzd));
          S++;
        }
      } else {
        // -------- fallback (bucket tie at Bmax; ~never): packed-exact loop --
#pragma unroll 1
        while (S < cap) {
          ull wpk = pk[0];
#pragma unroll
          for (int j = 1; j < RSLOTS; ++j) wpk = (pk[j] > wpk) ? pk[j] : wpk;
          ull g = wpk;
#pragma unroll
          for (int off = 1; off < 64; off <<= 1) {
            ull o = __shfl_xor(g, off);
            g = (o > g) ? o : g;
          }
          unsigned wkey = (unsigned)(g >> 32);
          if (S != 0 && !(wkey > BmaxKey)) break;
          int widx = 0xFFFF - (int)(g & 0xFFFFull);
          if (widx < 0) widx = 0;                      // sentinel clamp
          if (widx >= N_PTS) widx = N_PTS - 1;
          double wxd = (double)pos[3 * widx];
          double wyd = (double)pos[3 * widx + 1];
          double wzd = (double)pos[3 * widx + 2];
          if (gw == 0 && lane == 0) ST_RLX(anchors + nsel + S, widx);
#pragma unroll
          for (int j = 0; j < RSLOTS; ++j) {
            int p = 0xFFFF - (int)(pk[j] & 0xFFFFull);
            if (p < 0) p = 0;
            if (p >= N_PTS) p = N_PTS - 1;
            double d = dist64((double)pos[3 * p], (double)pos[3 * p + 1],
                              (double)pos[3 * p + 2], wxd, wyd, wzd);
            ull db  = (ull)__double_as_longlong(d);
            ull dpk = ((db | 0x8000000000000000ull) & PK_VMASK)
                    | (pk[j] & 0xFFFFull);
            ull nv  = (dpk < pk[j]) ? dpk : pk[j];
            pk[j] = (pk[j] == g) ? 0ull : nv;
          }
#pragma unroll
          for (int k2 = 0; k2 < PPT; ++k2)
            md[k2] = fmin(md[k2], dist64(pdx[k2], pdy[k2], pdz[k2], wxd, wyd, wzd));
          S++;
        }
      }
      nsel += S;

      // refresh thread-local argmax
      bv = -1.0e301; bi = 0x7fffffff;
#pragma unroll
      for (int k = 0; k < PPT; ++k) {
        int i = gtid + k * STRIDE;
        bool bt = (md[k] > bv) || (md[k] == bv && i < bi);
        bv = bt ? md[k] : bv; bi = bt ? i : bi;
      }
    }
  } else {
    // =============== KNN: one wave per anchor (no barriers) ===============
    const int aidx = blockIdx.x - NFB;
    int a = -1;
    for (;;) {
      if (lane == 0) a = LD_RLX(anchors + aidx);
      a = __shfl(a, 0);
      if (a >= 0) break;
      __builtin_amdgcn_s_sleep(32);
    }
    const int ai = a;
    const float ax = pos[3 * ai], ay = pos[3 * ai + 1], az = pos[3 * ai + 2];

    // per-lane top-20 (u64 keys, static indexing ONLY -> stays in VGPRs)
    ull key[KNN];
#pragma unroll
    for (int s = 0; s < KNN; ++s) key[s] = ~0ull;
    ull kmax = ~0ull; int smax = 0;
#pragma unroll 1
    for (int k = 0; k < N_PTS / 64; ++k) {   // 625 candidates per lane, exact
      int j = (k << 6) + lane;
      float dx = pos[3 * j] - ax, dy = pos[3 * j + 1] - ay, dz = pos[3 * j + 2] - az;
      float d  = dx * dx + dy * dy + dz * dz;
      ull nk = ((ull)__float_as_uint(d) << 32) | (unsigned)j;
      if (nk < kmax) {
#pragma unroll
        for (int s = 0; s < KNN; ++s) key[s] = (s == smax) ? nk : key[s];
        kmax = 0ull; smax = 0;
#pragma unroll
        for (int s = 0; s < KNN; ++s) {
          bool g = key[s] > kmax;
          kmax = g ? key[s] : kmax;
          smax = g ? s : smax;
        }
      }
    }

    // wave-wide merge: 20 extract-min rounds (shuffle butterfly, no LDS sync)
    ull lmin = ~0ull; int ls = 0;
#pragma unroll
    for (int s = 0; s < KNN; ++s) {
      bool l = key[s] < lmin;
      lmin = l ? key[s] : lmin; ls = l ? s : ls;
    }
#pragma unroll 1
    for (int r = 0; r < KNN; ++r) {
      ull g = lmin;
#pragma unroll
      for (int off = 1; off < 64; off <<= 1) {
        ull ov = __shfl_xor(g, off);
        g = (ov < g) ? ov : g;
      }
      if (lane == 0) sm.k.w[r] = (int)(g & 0xffffffffull);
      if (lmin == g) {          // unique owner consumes & rescans (all static)
#pragma unroll
        for (int s = 0; s < KNN; ++s) key[s] = (s == ls) ? ~0ull : key[s];
        lmin = ~0ull; ls = 0;
#pragma unroll
        for (int s = 0; s < KNN; ++s) {
          bool l = key[s] < lmin;
          lmin = l ? key[s] : lmin; ls = l ? s : ls;
        }
      }
    }

    if (lane == 0) {
      double mx = 0, my = 0, mz = 0;
      for (int r = 0; r < KNN; ++r) {
        int p = sm.k.w[r];
        mx += (double)pos[3 * p]; my += (double)pos[3 * p + 1]; mz += (double)pos[3 * p + 2];
      }
      mx /= KNN; my /= KNN; mz /= KNN;
      double xx = 0, xy = 0, xz = 0, yy = 0, yz = 0, zz = 0;
      for (int r = 0; r < KNN; ++r) {
        int p = sm.k.w[r];
        double cx = (double)pos[3 * p]     - mx;
        double cy = (double)pos[3 * p + 1] - my;
        double cz = (double)pos[3 * p + 2] - mz;
        xx += cx * cx; xy += cx * cy; xz += cx * cz;
        yy += cy * cy; yz += cy * cz; zz += cz * cz;
      }
      double v0, v1, v2;
      eig3_maxvec(xx, xy, xz, yy, yz, zz, v0, v1, v2);

      double a0 = vec_pred[3 * aidx], a1 = vec_pred[3 * aidx + 1], a2 = vec_pred[3 * aidx + 2];
      double an = sqrt(a0 * a0 + a1 * a1 + a2 * a2);
      double bn = sqrt(v0 * v0 + v1 * v1 + v2 * v2);
      double denom = fmax(an, 1e-8) * fmax(bn, 1e-8);
      double c = fabs((a0 * v0 + a1 * v1 + a2 * v2) / denom);
      atomicAdd(acc, log(c + 1e-6));
    }
  }
}

__global__ void finalize_kernel(const double* __restrict__ acc, float* __restrict__ out) {
  out[0] = (float)(-acc[0] / (double)N_ANCH);
}

// ===========================================================================
extern "C" void kernel_launch(void* const* d_in, const int* in_sizes, int n_in,
                              void* d_out, int out_size, void* d_ws, size_t ws_size,
                              hipStream_t stream) {
  (void)in_sizes; (void)n_in; (void)out_size; (void)ws_size;
  const float* vec_pred = (const float*)d_in[0];
  const float* pos      = (const float*)d_in[1];
  float* out = (float*)d_out;

  char* ws = (char*)d_ws;
  double* acc     = (double*)(ws + 0);
  int*    flag    = (int*)(ws + 64);
  ull*    slots   = (ull*)(ws + 1024);
  int*    anchors = (int*)(ws + 17408);

  hipMemsetAsync(ws, 0, 1024, stream);                   // acc + flags
  hipMemsetAsync(ws + 17408, 0xFF, N_ANCH * 4, stream);  // anchors = -1
  hipLaunchKernelGGL(fps_knn_kernel, dim3(NFB + N_ANCH), dim3(BT), 0, stream,
                     pos, vec_pred, flag, slots, anchors, acc);
  hipLaunchKernelGGL(finalize_kernel, dim3(1), dim3(1), 0, stream, acc, out);
}

// Round 9
// 2885.473 us; speedup vs baseline: 1.5403x; 1.5403x over previous
//
#include <hip/hip_runtime.h>
#include <math.h>

#define N_PTS       40000
#define N_ANCH      4000     // ceil(0.1 * 40000)
#define KNN         20
#define NFB         128      // fps blocks (1 wave each)
#define BT          64       // threads per block (all blocks) = 1 wave
#define NWAVES      128                // fps waves
#define STRIDE      (NWAVES * 64)      // 8192 = 2^13
#define PPT         5                  // 8192*5 = 40960 >= 40000
#define TW          4                  // published candidates per WAVE (R8: TW sweep is flat, 4 optimal)
#define POOL        (NWAVES * TW)      // 512
#define RSLOTS      (POOL / 64)        // 8 readback entries per lane
#define CCAP        6                  // compacted capacity/lane (384 hard bound)
                                       // R6/R8 cost law: alpha ~ 0.10 + 0.065*CCAP us/selection
                                       // -> keep CCAP minimal; this round halves the per-slot
                                       //    latency class via f32 arithmetic.

typedef unsigned long long ull;

#define LD_RLX(p)    __hip_atomic_load((p),  __ATOMIC_RELAXED, __HIP_MEMORY_SCOPE_AGENT)
#define ST_REL(p,v)  __hip_atomic_store((p), (v), __ATOMIC_RELEASE, __HIP_MEMORY_SCOPE_AGENT)
#define ST_RLX(p,v)  __hip_atomic_store((p), (v), __ATOMIC_RELAXED, __HIP_MEMORY_SCOPE_AGENT)

// Workspace layout (identical to R6):
//   off     0 : double acc               (zeroed)
//   off    64 : int flag[128]            (zeroed; per-wave monotone batch counters)
//   off  1024 : ull slots[2][512]        (parity x pool, packed {key32|pad16|idx16}; 8 KB)
//   off 17408 : int anchors[4000]        (memset 0xFF -> -1)
//
// f32 correctness: the REFERENCE computes all FPS distances in f32. Our exact-
// f64 kernel matched it bit-exact (absmax 0) for 9 rounds, and R7 proved even
// 28-bit-mantissa value quantization flips no selection -- argmax margins far
// exceed f32's ~2^-21 accumulated error. Tiebreak (value desc, idx asc) is
// exact in the packed u64 key; equal-f32 ties resolve by index, matching
// jnp.argmax's first-max rule.

__device__ __forceinline__ float dist32(float px, float py, float pz,
                                        float wx, float wy, float wz) {
  float dx = px - wx, dy = py - wy, dz = pz - wz;
  return dx * dx + dy * dy + dz * dz;
}

// monotone u32 key from f32 (exact order embedding)
__device__ __forceinline__ unsigned key32f(float v) {
  unsigned b = __float_as_uint(v);
  return (b & 0x80000000u) ? ~b : (b | 0x80000000u);
}

// packed sort key: (value-desc, idx-asc) as ONE u64.
//   pk = (key32f(v) << 32) | ((0xFFFF - idx) & 0xFFFF)
__device__ __forceinline__ ull pack_key32(unsigned key, int idx) {
  return ((ull)key << 32) | (ull)((0xFFFF - idx) & 0xFFFF);
}

// wave-wide max of u32 via DPP (VALU only); returns wave-uniform max
__device__ __forceinline__ unsigned wave_umax_dpp(unsigned x) {
#define DPP_STEP(ctrl) { unsigned y = (unsigned)__builtin_amdgcn_update_dpp( \
      0, (int)x, ctrl, 0xf, 0xf, true); x = (y > x) ? y : x; }
  DPP_STEP(0x111)  // row_shr:1
  DPP_STEP(0x112)  // row_shr:2
  DPP_STEP(0x114)  // row_shr:4
  DPP_STEP(0x118)  // row_shr:8
  DPP_STEP(0x142)  // row_bcast:15
  DPP_STEP(0x143)  // row_bcast:31
#undef DPP_STEP
  return (unsigned)__builtin_amdgcn_readlane((int)x, 63);
}

__device__ __forceinline__ int rl_i(int v, int l) { return __builtin_amdgcn_readlane(v, l); }
__device__ __forceinline__ float rl_f(float v, int l) {
  return __int_as_float(__builtin_amdgcn_readlane(__float_as_int(v), l));
}
__device__ __forceinline__ ull rl_u64(ull v, int l) {
  int lo = __builtin_amdgcn_readlane((int)(unsigned)(v & 0xffffffffull), l);
  int hi = __builtin_amdgcn_readlane((int)(unsigned)(v >> 32), l);
  return ((ull)(unsigned)hi << 32) | (unsigned)lo;
}

// wave winner of (v desc, idx asc) on f32: wave-uniform (wkey, wlane, widx).
// Exact: value compare via key32f; value ties resolved by min global idx.
__device__ __forceinline__ void wave_pick_f(float v, int idx,
                                            unsigned& wkey, int& wlane, int& widx) {
  unsigned k = key32f(v);
  unsigned M = wave_umax_dpp(k);
  ull mask = __ballot(k == M);
  if (__popcll(mask) == 1) {
    wlane = __ffsll(mask) - 1;
    widx  = rl_i(idx, wlane);
    wkey  = M;
  } else {
    int cand = (k == M) ? idx : 0x7fffffff;
#pragma unroll
    for (int off = 1; off < 64; off <<= 1) {
      int o = __shfl_xor(cand, off);
      cand = (o < cand) ? o : cand;
    }
    widx = cand;
    wkey = M;
    ull m2 = __ballot((idx == widx) && (k == M));
    wlane = __ffsll(m2) - 1;
  }
}

struct FpsSm {                 // single-wave compaction buffers (7680 B)
  ull    lv[CCAP * 64];        // packed keys
  float  lc[CCAP * 64][3];
};
struct KnnSm { int w[KNN]; };
union Smem { FpsSm f; KnnSm k; };

// ============== symmetric 3x3: eigenvector of largest eigenvalue ===========
__device__ static inline void eig3_maxvec(double xx, double xy, double xz,
                                          double yy, double yz, double zz,
                                          double& v0, double& v1, double& v2) {
  double q  = (xx + yy + zz) / 3.0;
  double p1 = xy * xy + xz * xz + yz * yz;
  double a00 = xx - q, a11 = yy - q, a22 = zz - q;
  double p2 = a00 * a00 + a11 * a11 + a22 * a22 + 2.0 * p1;
  if (p2 < 1e-300) { v0 = 1.0; v1 = 0.0; v2 = 0.0; return; }
  double p   = sqrt(p2 / 6.0);
  double inv = 1.0 / p;
  double b00 = a00 * inv, b01 = xy * inv, b02 = xz * inv;
  double b11 = a11 * inv, b12 = yz * inv, b22 = a22 * inv;
  double detB = b00 * (b11 * b22 - b12 * b12)
              - b01 * (b01 * b22 - b12 * b02)
              + b02 * (b01 * b12 - b11 * b02);
  double r = fmin(1.0, fmax(-1.0, detB * 0.5));
  double phi = acos(r) / 3.0;
  double lam = q + 2.0 * p * cos(phi);   // largest eigenvalue

  double r0x = xx - lam, r0y = xy,       r0z = xz;
  double r1x = xy,       r1y = yy - lam, r1z = yz;
  double r2x = xz,       r2y = yz,       r2z = zz - lam;
  double c0x = r0y * r1z - r0z * r1y, c0y = r0z * r1x - r0x * r1z, c0z = r0x * r1y - r0y * r1x;
  double c1x = r0y * r2z - r0z * r2y, c1y = r0z * r2x - r0x * r2z, c1z = r0x * r2y - r0y * r2x;
  double c2x = r1y * r2z - r1z * r2y, c2y = r1z * r2x - r1x * r2z, c2z = r1x * r2y - r1y * r2x;
  double n0 = c0x * c0x + c0y * c0y + c0z * c0z;
  double n1 = c1x * c1x + c1y * c1y + c1z * c1z;
  double n2 = c2x * c2x + c2y * c2y + c2z * c2z;
  double bx = c0x, by = c0y, bz = c0z, bn = n0;
  if (n1 > bn) { bx = c1x; by = c1y; bz = c1z; bn = n1; }
  if (n2 > bn) { bx = c2x; by = c2y; bz = c2z; bn = n2; }
  if (bn < 1e-280) { v0 = 1.0; v1 = 0.0; v2 = 0.0; return; }
  double s = 1.0 / sqrt(bn);
  v0 = bx * s; v1 = by * s; v2 = bz * s;
}

// ===========================================================================
__global__ __launch_bounds__(BT, 2) void fps_knn_kernel(
    const float* __restrict__ pos, const float* __restrict__ vec_pred,
    int* __restrict__ flag, ull* __restrict__ slots,
    int* __restrict__ anchors, double* __restrict__ acc) {
  __shared__ Smem sm;
  const int lane = threadIdx.x & 63;

  if (blockIdx.x < NFB) {
    // ============ FPS: one wave per block, wave-autonomous ================
    __builtin_amdgcn_s_setprio(1);   // FPS is the critical path (R0: +2-3%)

    const int gw   = blockIdx.x;       // global wave id, 0..127
    const int gtid = gw * 64 + lane;

    float pdx[PPT], pdy[PPT], pdz[PPT], md[PPT];   // f32 coords + min-dist
    const float a0x = pos[0], a0y = pos[1], a0z = pos[2];
#pragma unroll
    for (int k = 0; k < PPT; ++k) {
      int i = gtid + k * STRIDE;
      if (i < N_PTS) {
        pdx[k] = pos[3 * i];
        pdy[k] = pos[3 * i + 1];
        pdz[k] = pos[3 * i + 2];
        md[k]  = dist32(pdx[k], pdy[k], pdz[k], a0x, a0y, a0z);
      } else {
        pdx[k] = 0.0f; pdy[k] = 0.0f; pdz[k] = 0.0f;
        md[k]  = -3.0e38f;   // pad: never beats real md >= 0
      }
    }
    if (gw == 0 && lane == 0) ST_RLX(anchors + 0, 0);

    float bv = -3.3e38f; int bi = 0x7fffffff;
#pragma unroll
    for (int k = 0; k < PPT; ++k) {
      int i = gtid + k * STRIDE;
      bool bt = (md[k] > bv) || (md[k] == bv && i < bi);
      bv = bt ? md[k] : bv; bi = bt ? i : bi;
    }

    int nsel  = 1;
    int batch = 0;
#pragma unroll 1
    while (nsel < N_ANCH) {
      batch++;
      const int par = batch & 1;

      // ---- per-wave top-4 extraction (exact lex order) ----
      unsigned cons = 0;
      unsigned pkey = 0; int pix = 0;
#pragma unroll 1
      for (int r = 0; r < TW; ++r) {
        unsigned wkey; int wlane, widx;
        wave_pick_f(bv, bi, wkey, wlane, widx);
        if (lane == wlane && bi != 0x7fffffff) {
          cons |= 1u << ((unsigned)(bi - gtid) >> 13);   // STRIDE = 2^13
          bv = -3.3e38f; bi = 0x7fffffff;
#pragma unroll
          for (int k = 0; k < PPT; ++k) {
            if (!((cons >> k) & 1u)) {
              int i = gtid + k * STRIDE;
              bool bt = (md[k] > bv) || (md[k] == bv && i < bi);
              bv = bt ? md[k] : bv; bi = bt ? i : bi;
            }
          }
        }
        if (lane == r) { pkey = wkey; pix = widx; }
      }

      // ---- publish: ONE packed 8B store/lane; lane0 release flag orders ----
      if (lane < TW) {
        ST_RLX(&slots[par * POOL + gw * TW + lane], pack_key32(pkey, pix));
      }
      if (lane == 0) ST_REL(flag + gw, batch);   // s_waitcnt vmcnt(0) + store

      // ---- poll all 128 wave-flags (minimal footprint: 2 words/lane) -----
      for (;;) {
        int f0 = LD_RLX(flag + lane);
        int f1 = LD_RLX(flag + 64 + lane);
        if (__ballot((f0 >= batch) && (f1 >= batch)) == ~0ull) break;
        __builtin_amdgcn_s_sleep(1);
      }
      __builtin_amdgcn_sched_barrier(0);   // no compiler motion across the poll

      // ---- readback pool ONCE: packed u64 x 8 entries/lane ----
      ull pk[RSLOTS];
#pragma unroll
      for (int j = 0; j < RSLOTS; ++j)
        pk[j] = LD_RLX(&slots[par * POOL + lane + 64 * j]);

      // ---- bucket keys; Mkey (global max bucket) and BmaxKey ----
      unsigned kj[RSLOTS];
      unsigned lkmax = 0;
#pragma unroll
      for (int j = 0; j < RSLOTS; ++j) {
        kj[j] = (unsigned)(pk[j] >> 32);
        lkmax = (kj[j] > lkmax) ? kj[j] : lkmax;
      }
      const unsigned Mkey    = wave_umax_dpp(lkmax);
      const unsigned BmaxKey = wave_umax_dpp(((lane & 3) == 3) ? lkmax : 0u);

      int cap = N_ANCH - nsel;
      int S = 0;

      if (Mkey > BmaxKey) {
        // -------- typical path: compact live entries (key32 > BmaxKey) -----
        int base = 0;
#pragma unroll
        for (int j = 0; j < RSLOTS; ++j) {
          bool live = kj[j] > BmaxKey;
          ull bal = __ballot(live);
          int rank = base + (int)__popcll(bal & ((1ull << lane) - 1ull));
          if (live) {
            sm.f.lv[rank] = pk[j];
            int p = 0xFFFF - (int)(pk[j] & 0xFFFFull);
            sm.f.lc[rank][0] = pos[3 * p];
            sm.f.lc[rank][1] = pos[3 * p + 1];
            sm.f.lc[rank][2] = pos[3 * p + 2];
          }
          base += (int)__popcll(bal);
        }
        const int live_n = base;   // wave-uniform, 1..384

        // load compaction data to registers (packed key + f32 coords)
        ull pk2[CCAP]; float c2x[CCAP], c2y[CCAP], c2z[CCAP];
#pragma unroll
        for (int tt = 0; tt < CCAP; ++tt) {
          if (live_n > tt * 64) {
            int e = tt * 64 + lane;
            bool ok = e < live_n;
            ull    v  = sm.f.lv[e];
            float  x  = sm.f.lc[e][0];
            float  y  = sm.f.lc[e][1];
            float  z  = sm.f.lc[e][2];
            pk2[tt] = ok ? v : 0ull;
            c2x[tt] = ok ? x : 0.0f;
            c2y[tt] = ok ? y : 0.0f;
            c2z[tt] = ok ? z : 0.0f;
          } else {
            pk2[tt] = 0ull;
            c2x[tt] = 0.0f; c2y[tt] = 0.0f; c2z[tt] = 0.0f;
          }
        }

        // ---- S-loop: f32/int-key serial chain; md updated inline
        // (R4 lesson: inline md fills chain bubbles for free).
#pragma unroll 1
        while (S < cap) {
          // tree argmax over the 6 packed keys (carries f32 coords)
          ull pa, pb, pc, wpk; float ax_, ay_, az_, bx_, by_, bz_, fx, fy, fz;
          { bool t = pk2[1] > pk2[0];
            pa = t ? pk2[1] : pk2[0];
            ax_ = t ? c2x[1] : c2x[0]; ay_ = t ? c2y[1] : c2y[0]; az_ = t ? c2z[1] : c2z[0]; }
          { bool t = pk2[3] > pk2[2];
            pb = t ? pk2[3] : pk2[2];
            bx_ = t ? c2x[3] : c2x[2]; by_ = t ? c2y[3] : c2y[2]; bz_ = t ? c2z[3] : c2z[2]; }
          { bool t = pk2[5] > pk2[4];
            pc = t ? pk2[5] : pk2[4];
            fx = t ? c2x[5] : c2x[4]; fy = t ? c2y[5] : c2y[4]; fz = t ? c2z[5] : c2z[4]; }
          { bool t = pb > pa;
            pa = t ? pb : pa;
            ax_ = t ? bx_ : ax_; ay_ = t ? by_ : ay_; az_ = t ? bz_ : az_; }
          { bool t = pc > pa;
            wpk = t ? pc : pa;
            fx = t ? fx : ax_; fy = t ? fy : ay_; fz = t ? fz : az_; }

          // wave winner via u32 DPP on the packed key's top 32 bits
          unsigned k = (unsigned)(wpk >> 32);
          unsigned M = wave_umax_dpp(k);
          ull mask = __ballot(k == M);
          ull full; int wlane;
          if (__popcll(mask) == 1) {
            wlane = __ffsll(mask) - 1;
            full  = rl_u64(wpk, wlane);
          } else {
            // value tie: butterfly max on the full packed key (exact idx-asc)
            ull g = wpk;
#pragma unroll
            for (int off = 1; off < 64; off <<= 1) {
              ull o = __shfl_xor(g, off);
              g = (o > g) ? o : g;
            }
            full = g;
            ull m2 = __ballot(wpk == full);
            wlane = __ffsll(m2) - 1;
          }
          unsigned wkey = (unsigned)(full >> 32);
          if (S != 0 && !(wkey > BmaxKey)) break;
          int widx = 0xFFFF - (int)(full & 0xFFFFull);
          float wx = rl_f(fx, wlane), wy = rl_f(fy, wlane), wz = rl_f(fz, wlane);
          if (gw == 0 && lane == 0) ST_RLX(anchors + nsel + S, widx);

          // update packed keys: u64 min against new-anchor f32 distance key;
          // winner slot dies (-> 0). Dead slots stay 0 (min(0,x)=0).
#pragma unroll
          for (int tt = 0; tt < CCAP; ++tt) {
            if (live_n > tt * 64) {
              float d = dist32(c2x[tt], c2y[tt], c2z[tt], wx, wy, wz);
              ull dpk = ((ull)key32f(d) << 32) | (pk2[tt] & 0xFFFFull);
              ull nv  = (dpk < pk2[tt]) ? dpk : pk2[tt];
              pk2[tt] = (pk2[tt] == full) ? 0ull : nv;
            }
          }
          // inline apply to own md slice (bubble-filler under the chain)
#pragma unroll
          for (int k2 = 0; k2 < PPT; ++k2)
            md[k2] = fminf(md[k2], dist32(pdx[k2], pdy[k2], pdz[k2], wx, wy, wz));
          S++;
        }
      } else {
        // -------- fallback (bucket tie at Bmax; rare): packed-exact loop ----
#pragma unroll 1
        while (S < cap) {
          ull wpk = pk[0];
#pragma unroll
          for (int j = 1; j < RSLOTS; ++j) wpk = (pk[j] > wpk) ? pk[j] : wpk;
          ull g = wpk;
#pragma unroll
          for (int off = 1; off < 64; off <<= 1) {
            ull o = __shfl_xor(g, off);
            g = (o > g) ? o : g;
          }
          unsigned wkey = (unsigned)(g >> 32);
          if (S != 0 && !(wkey > BmaxKey)) break;
          int widx = 0xFFFF - (int)(g & 0xFFFFull);
          if (widx < 0) widx = 0;                      // sentinel clamp
          if (widx >= N_PTS) widx = N_PTS - 1;
          float wx = pos[3 * widx];
          float wy = pos[3 * widx + 1];
          float wz = pos[3 * widx + 2];
          if (gw == 0 && lane == 0) ST_RLX(anchors + nsel + S, widx);
#pragma unroll
          for (int j = 0; j < RSLOTS; ++j) {
            int p = 0xFFFF - (int)(pk[j] & 0xFFFFull);
            if (p < 0) p = 0;
            if (p >= N_PTS) p = N_PTS - 1;
            float d = dist32(pos[3 * p], pos[3 * p + 1], pos[3 * p + 2], wx, wy, wz);
            ull dpk = ((ull)key32f(d) << 32) | (pk[j] & 0xFFFFull);
            ull nv  = (dpk < pk[j]) ? dpk : pk[j];
            pk[j] = (pk[j] == g) ? 0ull : nv;
          }
#pragma unroll
          for (int k2 = 0; k2 < PPT; ++k2)
            md[k2] = fminf(md[k2], dist32(pdx[k2], pdy[k2], pdz[k2], wx, wy, wz));
          S++;
        }
      }
      nsel += S;

      // refresh thread-local argmax
      bv = -3.3e38f; bi = 0x7fffffff;
#pragma unroll
      for (int k = 0; k < PPT; ++k) {
        int i = gtid + k * STRIDE;
        bool bt = (md[k] > bv) || (md[k] == bv && i < bi);
        bv = bt ? md[k] : bv; bi = bt ? i : bi;
      }
    }
  } else {
    // =============== KNN: one wave per anchor (no barriers) ===============
    const int aidx = blockIdx.x - NFB;
    int a = -1;
    for (;;) {
      if (lane == 0) a = LD_RLX(anchors + aidx);
      a = __shfl(a, 0);
      if (a >= 0) break;
      __builtin_amdgcn_s_sleep(32);
    }
    const int ai = a;
    const float ax = pos[3 * ai], ay = pos[3 * ai + 1], az = pos[3 * ai + 2];

    // per-lane top-20 (u64 keys, static indexing ONLY -> stays in VGPRs)
    ull key[KNN];
#pragma unroll
    for (int s = 0; s < KNN; ++s) key[s] = ~0ull;
    ull kmax = ~0ull; int smax = 0;
#pragma unroll 1
    for (int k = 0; k < N_PTS / 64; ++k) {   // 625 candidates per lane, exact
      int j = (k << 6) + lane;
      float dx = pos[3 * j] - ax, dy = pos[3 * j + 1] - ay, dz = pos[3 * j + 2] - az;
      float d  = dx * dx + dy * dy + dz * dz;
      ull nk = ((ull)__float_as_uint(d) << 32) | (unsigned)j;
      if (nk < kmax) {
#pragma unroll
        for (int s = 0; s < KNN; ++s) key[s] = (s == smax) ? nk : key[s];
        kmax = 0ull; smax = 0;
#pragma unroll
        for (int s = 0; s < KNN; ++s) {
          bool g = key[s] > kmax;
          kmax = g ? key[s] : kmax;
          smax = g ? s : smax;
        }
      }
    }

    // wave-wide merge: 20 extract-min rounds (shuffle butterfly, no LDS sync)
    ull lmin = ~0ull; int ls = 0;
#pragma unroll
    for (int s = 0; s < KNN; ++s) {
      bool l = key[s] < lmin;
      lmin = l ? key[s] : lmin; ls = l ? s : ls;
    }
#pragma unroll 1
    for (int r = 0; r < KNN; ++r) {
      ull g = lmin;
#pragma unroll
      for (int off = 1; off < 64; off <<= 1) {
        ull ov = __shfl_xor(g, off);
        g = (ov < g) ? ov : g;
      }
      if (lane == 0) sm.k.w[r] = (int)(g & 0xffffffffull);
      if (lmin == g) {          // unique owner consumes & rescans (all static)
#pragma unroll
        for (int s = 0; s < KNN; ++s) key[s] = (s == ls) ? ~0ull : key[s];
        lmin = ~0ull; ls = 0;
#pragma unroll
        for (int s = 0; s < KNN; ++s) {
          bool l = key[s] < lmin;
          lmin = l ? key[s] : lmin; ls = l ? s : ls;
        }
      }
    }

    if (lane == 0) {
      double mx = 0, my = 0, mz = 0;
      for (int r = 0; r < KNN; ++r) {
        int p = sm.k.w[r];
        mx += (double)pos[3 * p]; my += (double)pos[3 * p + 1]; mz += (double)pos[3 * p + 2];
      }
      mx /= KNN; my /= KNN; mz /= KNN;
      double xx = 0, xy = 0, xz = 0, yy = 0, yz = 0, zz = 0;
      for (int r = 0; r < KNN; ++r) {
        int p = sm.k.w[r];
        double cx = (double)pos[3 * p]     - mx;
        double cy = (double)pos[3 * p + 1] - my;
        double cz = (double)pos[3 * p + 2] - mz;
        xx += cx * cx; xy += cx * cy; xz += cx * cz;
        yy += cy * cy; yz += cy * cz; zz += cz * cz;
      }
      double v0, v1, v2;
      eig3_maxvec(xx, xy, xz, yy, yz, zz, v0, v1, v2);

      double a0 = vec_pred[3 * aidx], a1 = vec_pred[3 * aidx + 1], a2 = vec_pred[3 * aidx + 2];
      double an = sqrt(a0 * a0 + a1 * a1 + a2 * a2);
      double bn = sqrt(v0 * v0 + v1 * v1 + v2 * v2);
      double denom = fmax(an, 1e-8) * fmax(bn, 1e-8);
      double c = fabs((a0 * v0 + a1 * v1 + a2 * v2) / denom);
      atomicAdd(acc, log(c + 1e-6));
    }
  }
}

__global__ void finalize_kernel(const double* __restrict__ acc, float* __restrict__ out) {
  out[0] = (float)(-acc[0] / (double)N_ANCH);
}

// ===========================================================================
extern "C" void kernel_launch(void* const* d_in, const int* in_sizes, int n_in,
                              void* d_out, int out_size, void* d_ws, size_t ws_size,
                              hipStream_t stream) {
  (void)in_sizes; (void)n_in; (void)out_size; (void)ws_size;
  const float* vec_pred = (const float*)d_in[0];
  const float* pos      = (const float*)d_in[1];
  float* out = (float*)d_out;

  char* ws = (char*)d_ws;
  double* acc     = (double*)(ws + 0);
  int*    flag    = (int*)(ws + 64);
  ull*    slots   = (ull*)(ws + 1024);
  int*    anchors = (int*)(ws + 17408);

  hipMemsetAsync(ws, 0, 1024, stream);                   // acc + flags
  hipMemsetAsync(ws + 17408, 0xFF, N_ANCH * 4, stream);  // anchors = -1
  hipLaunchKernelGGL(fps_knn_kernel, dim3(NFB + N_ANCH), dim3(BT), 0, stream,
                     pos, vec_pred, flag, slots, anchors, acc);
  hipLaunchKernelGGL(finalize_kernel, dim3(1), dim3(1), 0, stream, acc, out);
}

// Round 10
// 2687.065 us; speedup vs baseline: 1.6540x; 1.0738x over previous
//
#include <hip/hip_runtime.h>
#include <math.h>

#define N_PTS       40000
#define N_ANCH      4000     // ceil(0.1 * 40000)
#define KNN         20
#define NFB         128      // fps blocks (1 wave each)
#define BT          64       // threads per block (all blocks) = 1 wave
#define NWAVES      128                // fps waves
#define STRIDE      (NWAVES * 64)      // 8192 = 2^13
#define PPT         5                  // 8192*5 = 40960 >= 40000
#define TW          4                  // published candidates per WAVE
#define POOL        (NWAVES * TW)      // 512
#define RSLOTS      (POOL / 64)        // 8 readback entries per lane
#define CCAP        6                  // compacted capacity/lane (384 hard bound)

typedef unsigned long long ull;

#define LD_RLX(p)    __hip_atomic_load((p),  __ATOMIC_RELAXED, __HIP_MEMORY_SCOPE_AGENT)
#define ST_REL(p,v)  __hip_atomic_store((p), (v), __ATOMIC_RELEASE, __HIP_MEMORY_SCOPE_AGENT)
#define ST_RLX(p,v)  __hip_atomic_store((p), (v), __ATOMIC_RELAXED, __HIP_MEMORY_SCOPE_AGENT)

// Workspace layout (identical to R6/R9):
//   off     0 : double acc               (zeroed)
//   off    64 : int flag[128]            (zeroed; per-wave monotone batch counters)
//   off  1024 : ull slots[2][512]        (parity x pool, packed {key32|idx16}; 8 KB)
//   off 17408 : int anchors[4000]        (memset 0xFF -> -1)
//
// R9 lesson: the S-loop serial chain is cross-lane/scalar-round-trip bound
// (ballot/ffs/readlane transitions), not arithmetic-bound. This round removes
// ALL of them from the hot loop:
//  - rank baked into compacted key bits 0..15 -> winner coords via broadcast
//    LDS read instead of 3 readlanes; widx from the key itself.
//  - winner selection = two 32-bit DPP max chains (value-phase, then
//    lo32-phase among value-max holders) -> exact (key desc, idx asc) order
//    with zero ballots / ffs / per-lane readlanes.

__device__ __forceinline__ float dist32(float px, float py, float pz,
                                        float wx, float wy, float wz) {
  float dx = px - wx, dy = py - wy, dz = pz - wz;
  return dx * dx + dy * dy + dz * dz;
}

// monotone u32 key from f32 (exact order embedding)
__device__ __forceinline__ unsigned key32f(float v) {
  unsigned b = __float_as_uint(v);
  return (b & 0x80000000u) ? ~b : (b | 0x80000000u);
}

// published slot: (value-desc, idx-asc) as ONE u64.
//   pk = (key32f(v) << 32) | ((0xFFFF - idx) & 0xFFFF)
__device__ __forceinline__ ull pack_key32(unsigned key, int idx) {
  return ((ull)key << 32) | (ull)((0xFFFF - idx) & 0xFFFF);
}

// wave-wide max of u32 via DPP (VALU only); returns wave-uniform max
__device__ __forceinline__ unsigned wave_umax_dpp(unsigned x) {
#define DPP_STEP(ctrl) { unsigned y = (unsigned)__builtin_amdgcn_update_dpp( \
      0, (int)x, ctrl, 0xf, 0xf, true); x = (y > x) ? y : x; }
  DPP_STEP(0x111)  // row_shr:1
  DPP_STEP(0x112)  // row_shr:2
  DPP_STEP(0x114)  // row_shr:4
  DPP_STEP(0x118)  // row_shr:8
  DPP_STEP(0x142)  // row_bcast:15
  DPP_STEP(0x143)  // row_bcast:31
#undef DPP_STEP
  return (unsigned)__builtin_amdgcn_readlane((int)x, 63);
}

struct FpsSm {                 // single-wave compaction buffers (7680 B)
  ull    lv[CCAP * 64];        // packed keys (with rank in low 16)
  float  lc[CCAP * 64][3];     // coords indexed by rank
};
struct KnnSm { int w[KNN]; };
union Smem { FpsSm f; KnnSm k; };

// ============== symmetric 3x3: eigenvector of largest eigenvalue ===========
__device__ static inline void eig3_maxvec(double xx, double xy, double xz,
                                          double yy, double yz, double zz,
                                          double& v0, double& v1, double& v2) {
  double q  = (xx + yy + zz) / 3.0;
  double p1 = xy * xy + xz * xz + yz * yz;
  double a00 = xx - q, a11 = yy - q, a22 = zz - q;
  double p2 = a00 * a00 + a11 * a11 + a22 * a22 + 2.0 * p1;
  if (p2 < 1e-300) { v0 = 1.0; v1 = 0.0; v2 = 0.0; return; }
  double p   = sqrt(p2 / 6.0);
  double inv = 1.0 / p;
  double b00 = a00 * inv, b01 = xy * inv, b02 = xz * inv;
  double b11 = a11 * inv, b12 = yz * inv, b22 = a22 * inv;
  double detB = b00 * (b11 * b22 - b12 * b12)
              - b01 * (b01 * b22 - b12 * b02)
              + b02 * (b01 * b12 - b11 * b02);
  double r = fmin(1.0, fmax(-1.0, detB * 0.5));
  double phi = acos(r) / 3.0;
  double lam = q + 2.0 * p * cos(phi);   // largest eigenvalue

  double r0x = xx - lam, r0y = xy,       r0z = xz;
  double r1x = xy,       r1y = yy - lam, r1z = yz;
  double r2x = xz,       r2y = yz,       r2z = zz - lam;
  double c0x = r0y * r1z - r0z * r1y, c0y = r0z * r1x - r0x * r1z, c0z = r0x * r1y - r0y * r1x;
  double c1x = r0y * r2z - r0z * r2y, c1y = r0z * r2x - r0x * r2z, c1z = r0x * r2y - r0y * r2x;
  double c2x = r1y * r2z - r1z * r2y, c2y = r1z * r2x - r1x * r2z, c2z = r1x * r2y - r1y * r2x;
  double n0 = c0x * c0x + c0y * c0y + c0z * c0z;
  double n1 = c1x * c1x + c1y * c1y + c1z * c1z;
  double n2 = c2x * c2x + c2y * c2y + c2z * c2z;
  double bx = c0x, by = c0y, bz = c0z, bn = n0;
  if (n1 > bn) { bx = c1x; by = c1y; bz = c1z; bn = n1; }
  if (n2 > bn) { bx = c2x; by = c2y; bz = c2z; bn = n2; }
  if (bn < 1e-280) { v0 = 1.0; v1 = 0.0; v2 = 0.0; return; }
  double s = 1.0 / sqrt(bn);
  v0 = bx * s; v1 = by * s; v2 = bz * s;
}

// ===========================================================================
__global__ __launch_bounds__(BT, 2) void fps_knn_kernel(
    const float* __restrict__ pos, const float* __restrict__ vec_pred,
    int* __restrict__ flag, ull* __restrict__ slots,
    int* __restrict__ anchors, double* __restrict__ acc) {
  __shared__ Smem sm;
  const int lane = threadIdx.x & 63;

  if (blockIdx.x < NFB) {
    // ============ FPS: one wave per block, wave-autonomous ================
    __builtin_amdgcn_s_setprio(1);   // FPS is the critical path (R0: +2-3%)

    const int gw   = blockIdx.x;       // global wave id, 0..127
    const int gtid = gw * 64 + lane;

    float pdx[PPT], pdy[PPT], pdz[PPT], md[PPT];   // f32 coords + min-dist
    const float a0x = pos[0], a0y = pos[1], a0z = pos[2];
#pragma unroll
    for (int k = 0; k < PPT; ++k) {
      int i = gtid + k * STRIDE;
      if (i < N_PTS) {
        pdx[k] = pos[3 * i];
        pdy[k] = pos[3 * i + 1];
        pdz[k] = pos[3 * i + 2];
        md[k]  = dist32(pdx[k], pdy[k], pdz[k], a0x, a0y, a0z);
      } else {
        pdx[k] = 0.0f; pdy[k] = 0.0f; pdz[k] = 0.0f;
        md[k]  = -3.0e38f;   // pad: never beats real md >= 0
      }
    }
    if (gw == 0 && lane == 0) ST_RLX(anchors + 0, 0);

    float bv = -3.3e38f; int bi = 0x7fffffff;
#pragma unroll
    for (int k = 0; k < PPT; ++k) {
      int i = gtid + k * STRIDE;
      bool bt = (md[k] > bv) || (md[k] == bv && i < bi);
      bv = bt ? md[k] : bv; bi = bt ? i : bi;
    }

    int nsel  = 1;
    int batch = 0;
#pragma unroll 1
    while (nsel < N_ANCH) {
      batch++;
      const int par = batch & 1;

      // ---- per-wave top-4 extraction: two-phase DPP, no ballot/readlane ---
      unsigned cons = 0;
      unsigned pkey = 0; int pix = 0;
#pragma unroll 1
      for (int r = 0; r < TW; ++r) {
        unsigned k = key32f(bv);
        unsigned M = wave_umax_dpp(k);
        unsigned cand = (k == M) ? ~(unsigned)bi : 0u;   // max(~bi) = min bi
        unsigned L = wave_umax_dpp(cand);
        int widx = (int)~L;
        if (lane == r) { pkey = M; pix = widx; }
        if (k == M && bi == widx && bi != 0x7fffffff) {  // consuming lane
          cons |= 1u << ((unsigned)(bi - gtid) >> 13);   // STRIDE = 2^13
          bv = -3.3e38f; bi = 0x7fffffff;
#pragma unroll
          for (int kk = 0; kk < PPT; ++kk) {
            if (!((cons >> kk) & 1u)) {
              int i = gtid + kk * STRIDE;
              bool bt = (md[kk] > bv) || (md[kk] == bv && i < bi);
              bv = bt ? md[kk] : bv; bi = bt ? i : bi;
            }
          }
        }
      }

      // ---- publish: ONE packed 8B store/lane; lane0 release flag orders ----
      if (lane < TW) {
        ST_RLX(&slots[par * POOL + gw * TW + lane], pack_key32(pkey, pix));
      }
      if (lane == 0) ST_REL(flag + gw, batch);   // s_waitcnt vmcnt(0) + store

      // ---- poll all 128 wave-flags (minimal footprint: 2 words/lane) -----
      for (;;) {
        int f0 = LD_RLX(flag + lane);
        int f1 = LD_RLX(flag + 64 + lane);
        if (__ballot((f0 >= batch) && (f1 >= batch)) == ~0ull) break;
        __builtin_amdgcn_s_sleep(1);
      }
      __builtin_amdgcn_sched_barrier(0);   // no compiler motion across the poll

      // ---- readback pool ONCE: packed u64 x 8 entries/lane ----
      ull pk[RSLOTS];
#pragma unroll
      for (int j = 0; j < RSLOTS; ++j)
        pk[j] = LD_RLX(&slots[par * POOL + lane + 64 * j]);

      // ---- bucket keys; Mkey (global max bucket) and BmaxKey ----
      unsigned kj[RSLOTS];
      unsigned lkmax = 0;
#pragma unroll
      for (int j = 0; j < RSLOTS; ++j) {
        kj[j] = (unsigned)(pk[j] >> 32);
        lkmax = (kj[j] > lkmax) ? kj[j] : lkmax;
      }
      const unsigned Mkey    = wave_umax_dpp(lkmax);
      const unsigned BmaxKey = wave_umax_dpp(((lane & 3) == 3) ? lkmax : 0u);

      int cap = N_ANCH - nsel;
      int S = 0;

      if (Mkey > BmaxKey) {
        // -------- typical path: compact live entries (key32 > BmaxKey) -----
        // compacted key layout: key32<<32 | (0xFFFF-idx)<<16 | rank
        // (rank = LDS position of this entry's coords; order unaffected
        //  since idx is unique -> rank never decides a comparison)
        int base = 0;
#pragma unroll
        for (int j = 0; j < RSLOTS; ++j) {
          bool live = kj[j] > BmaxKey;
          ull bal = __ballot(live);
          int rank = base + (int)__popcll(bal & ((1ull << lane) - 1ull));
          if (live) {
            sm.f.lv[rank] = (pk[j] & 0xFFFFFFFF00000000ull)
                          | ((pk[j] & 0xFFFFull) << 16) | (ull)(unsigned)rank;
            int p = 0xFFFF - (int)(pk[j] & 0xFFFFull);
            sm.f.lc[rank][0] = pos[3 * p];
            sm.f.lc[rank][1] = pos[3 * p + 1];
            sm.f.lc[rank][2] = pos[3 * p + 2];
          }
          base += (int)__popcll(bal);
        }
        const int live_n = base;   // wave-uniform, 1..384

        // load compaction data to registers (packed key + f32 coords)
        ull pk2[CCAP]; float c2x[CCAP], c2y[CCAP], c2z[CCAP];
#pragma unroll
        for (int tt = 0; tt < CCAP; ++tt) {
          if (live_n > tt * 64) {
            int e = tt * 64 + lane;
            bool ok = e < live_n;
            ull    v  = sm.f.lv[e];
            float  x  = sm.f.lc[e][0];
            float  y  = sm.f.lc[e][1];
            float  z  = sm.f.lc[e][2];
            pk2[tt] = ok ? v : 0ull;
            c2x[tt] = ok ? x : 0.0f;
            c2y[tt] = ok ? y : 0.0f;
            c2z[tt] = ok ? z : 0.0f;
          } else {
            pk2[tt] = 0ull;
            c2x[tt] = 0.0f; c2y[tt] = 0.0f; c2z[tt] = 0.0f;
          }
        }

        // ---- S-loop: zero-ballot zero-readlane chain; md inline (R4) ----
#pragma unroll 1
        while (S < cap) {
          // in-lane max over 6 packed keys
          ull wpk = pk2[0];
#pragma unroll
          for (int tt = 1; tt < CCAP; ++tt)
            wpk = (pk2[tt] > wpk) ? pk2[tt] : wpk;

          // phase 1: wave max of value key (hi32)
          unsigned hi = (unsigned)(wpk >> 32);
          unsigned M  = wave_umax_dpp(hi);
          if (S != 0 && !(M > BmaxKey)) break;
          // phase 2: among value-max holders, max lo32 = (idx-asc, rank)
          unsigned lo = (hi == M) ? (unsigned)wpk : 0u;
          unsigned L  = wave_umax_dpp(lo);
          ull full = ((ull)M << 32) | (ull)L;
          int widx = 0xFFFF - (int)((L >> 16) & 0xFFFFu);
          int rank = (int)(L & 0xFFFFu);
          float wx = sm.f.lc[rank][0];    // broadcast LDS read (no conflict)
          float wy = sm.f.lc[rank][1];
          float wz = sm.f.lc[rank][2];
          if (gw == 0 && lane == 0) ST_RLX(anchors + nsel + S, widx);

          // update packed keys: u64 min vs new-anchor distance key (low32
          // preserved: idx+rank). Winner dies (-> 0); dead slots stay 0.
#pragma unroll
          for (int tt = 0; tt < CCAP; ++tt) {
            if (live_n > tt * 64) {
              float d = dist32(c2x[tt], c2y[tt], c2z[tt], wx, wy, wz);
              ull dpk = ((ull)key32f(d) << 32) | (pk2[tt] & 0xFFFFFFFFull);
              ull nv  = (dpk < pk2[tt]) ? dpk : pk2[tt];
              pk2[tt] = (pk2[tt] == full) ? 0ull : nv;
            }
          }
          // inline apply to own md slice (bubble-filler under the chain)
#pragma unroll
          for (int k2 = 0; k2 < PPT; ++k2)
            md[k2] = fminf(md[k2], dist32(pdx[k2], pdy[k2], pdz[k2], wx, wy, wz));
          S++;
        }
      } else {
        // -------- fallback (bucket tie at Bmax; rare): packed-exact loop ----
        // operates on raw pool words {key32|idx16}; exact u64 butterfly.
#pragma unroll 1
        while (S < cap) {
          ull wpk = pk[0];
#pragma unroll
          for (int j = 1; j < RSLOTS; ++j) wpk = (pk[j] > wpk) ? pk[j] : wpk;
          ull g = wpk;
#pragma unroll
          for (int off = 1; off < 64; off <<= 1) {
            ull o = __shfl_xor(g, off);
            g = (o > g) ? o : g;
          }
          unsigned wkey = (unsigned)(g >> 32);
          if (S != 0 && !(wkey > BmaxKey)) break;
          int widx = 0xFFFF - (int)(g & 0xFFFFull);
          if (widx < 0) widx = 0;                      // sentinel clamp
          if (widx >= N_PTS) widx = N_PTS - 1;
          float wx = pos[3 * widx];
          float wy = pos[3 * widx + 1];
          float wz = pos[3 * widx + 2];
          if (gw == 0 && lane == 0) ST_RLX(anchors + nsel + S, widx);
#pragma unroll
          for (int j = 0; j < RSLOTS; ++j) {
            int p = 0xFFFF - (int)(pk[j] & 0xFFFFull);
            if (p < 0) p = 0;
            if (p >= N_PTS) p = N_PTS - 1;
            float d = dist32(pos[3 * p], pos[3 * p + 1], pos[3 * p + 2], wx, wy, wz);
            ull dpk = ((ull)key32f(d) << 32) | (pk[j] & 0xFFFFull);
            ull nv  = (dpk < pk[j]) ? dpk : pk[j];
            pk[j] = (pk[j] == g) ? 0ull : nv;
          }
#pragma unroll
          for (int k2 = 0; k2 < PPT; ++k2)
            md[k2] = fminf(md[k2], dist32(pdx[k2], pdy[k2], pdz[k2], wx, wy, wz));
          S++;
        }
      }
      nsel += S;

      // refresh thread-local argmax
      bv = -3.3e38f; bi = 0x7fffffff;
#pragma unroll
      for (int k = 0; k < PPT; ++k) {
        int i = gtid + k * STRIDE;
        bool bt = (md[k] > bv) || (md[k] == bv && i < bi);
        bv = bt ? md[k] : bv; bi = bt ? i : bi;
      }
    }
  } else {
    // =============== KNN: one wave per anchor (no barriers) ===============
    const int aidx = blockIdx.x - NFB;
    int a = -1;
    for (;;) {
      if (lane == 0) a = LD_RLX(anchors + aidx);
      a = __shfl(a, 0);
      if (a >= 0) break;
      __builtin_amdgcn_s_sleep(32);
    }
    const int ai = a;
    const float ax = pos[3 * ai], ay = pos[3 * ai + 1], az = pos[3 * ai + 2];

    // per-lane top-20 (u64 keys, static indexing ONLY -> stays in VGPRs)
    ull key[KNN];
#pragma unroll
    for (int s = 0; s < KNN; ++s) key[s] = ~0ull;
    ull kmax = ~0ull; int smax = 0;
#pragma unroll 1
    for (int k = 0; k < N_PTS / 64; ++k) {   // 625 candidates per lane, exact
      int j = (k << 6) + lane;
      float dx = pos[3 * j] - ax, dy = pos[3 * j + 1] - ay, dz = pos[3 * j + 2] - az;
      float d  = dx * dx + dy * dy + dz * dz;
      ull nk = ((ull)__float_as_uint(d) << 32) | (unsigned)j;
      if (nk < kmax) {
#pragma unroll
        for (int s = 0; s < KNN; ++s) key[s] = (s == smax) ? nk : key[s];
        kmax = 0ull; smax = 0;
#pragma unroll
        for (int s = 0; s < KNN; ++s) {
          bool g = key[s] > kmax;
          kmax = g ? key[s] : kmax;
          smax = g ? s : smax;
        }
      }
    }

    // wave-wide merge: 20 extract-min rounds (shuffle butterfly, no LDS sync)
    ull lmin = ~0ull; int ls = 0;
#pragma unroll
    for (int s = 0; s < KNN; ++s) {
      bool l = key[s] < lmin;
      lmin = l ? key[s] : lmin; ls = l ? s : ls;
    }
#pragma unroll 1
    for (int r = 0; r < KNN; ++r) {
      ull g = lmin;
#pragma unroll
      for (int off = 1; off < 64; off <<= 1) {
        ull ov = __shfl_xor(g, off);
        g = (ov < g) ? ov : g;
      }
      if (lane == 0) sm.k.w[r] = (int)(g & 0xffffffffull);
      if (lmin == g) {          // unique owner consumes & rescans (all static)
#pragma unroll
        for (int s = 0; s < KNN; ++s) key[s] = (s == ls) ? ~0ull : key[s];
        lmin = ~0ull; ls = 0;
#pragma unroll
        for (int s = 0; s < KNN; ++s) {
          bool l = key[s] < lmin;
          lmin = l ? key[s] : lmin; ls = l ? s : ls;
        }
      }
    }

    if (lane == 0) {
      double mx = 0, my = 0, mz = 0;
      for (int r = 0; r < KNN; ++r) {
        int p = sm.k.w[r];
        mx += (double)pos[3 * p]; my += (double)pos[3 * p + 1]; mz += (double)pos[3 * p + 2];
      }
      mx /= KNN; my /= KNN; mz /= KNN;
      double xx = 0, xy = 0, xz = 0, yy = 0, yz = 0, zz = 0;
      for (int r = 0; r < KNN; ++r) {
        int p = sm.k.w[r];
        double cx = (double)pos[3 * p]     - mx;
        double cy = (double)pos[3 * p + 1] - my;
        double cz = (double)pos[3 * p + 2] - mz;
        xx += cx * cx; xy += cx * cy; xz += cx * cz;
        yy += cy * cy; yz += cy * cz; zz += cz * cz;
      }
      double v0, v1, v2;
      eig3_maxvec(xx, xy, xz, yy, yz, zz, v0, v1, v2);

      double a0 = vec_pred[3 * aidx], a1 = vec_pred[3 * aidx + 1], a2 = vec_pred[3 * aidx + 2];
      double an = sqrt(a0 * a0 + a1 * a1 + a2 * a2);
      double bn = sqrt(v0 * v0 + v1 * v1 + v2 * v2);
      double denom = fmax(an, 1e-8) * fmax(bn, 1e-8);
      double c = fabs((a0 * v0 + a1 * v1 + a2 * v2) / denom);
      atomicAdd(acc, log(c + 1e-6));
    }
  }
}

__global__ void finalize_kernel(const double* __restrict__ acc, float* __restrict__ out) {
  out[0] = (float)(-acc[0] / (double)N_ANCH);
}

// ===========================================================================
extern "C" void kernel_launch(void* const* d_in, const int* in_sizes, int n_in,
                              void* d_out, int out_size, void* d_ws, size_t ws_size,
                              hipStream_t stream) {
  (void)in_sizes; (void)n_in; (void)out_size; (void)ws_size;
  const float* vec_pred = (const float*)d_in[0];
  const float* pos      = (const float*)d_in[1];
  float* out = (float*)d_out;

  char* ws = (char*)d_ws;
  double* acc     = (double*)(ws + 0);
  int*    flag    = (int*)(ws + 64);
  ull*    slots   = (ull*)(ws + 1024);
  int*    anchors = (int*)(ws + 17408);

  hipMemsetAsync(ws, 0, 1024, stream);                   // acc + flags
  hipMemsetAsync(ws + 17408, 0xFF, N_ANCH * 4, stream);  // anchors = -1
  hipLaunchKernelGGL(fps_knn_kernel, dim3(NFB + N_ANCH), dim3(BT), 0, stream,
                     pos, vec_pred, flag, slots, anchors, acc);
  hipLaunchKernelGGL(finalize_kernel, dim3(1), dim3(1), 0, stream, acc, out);
}